// Round 12
// baseline (3806.189 us; speedup 1.0000x reference)
//
#include <hip/hip_runtime.h>
#include <math.h>

#define B_ 1024
#define D_ 2048
#define H_ 2048
#define E_ 16
#define K_ 8
#define KEEP_ 6
#define EXP_ID_ 0

// ---------------- ws layout ----------------
#define WS_OUTALL 0
#define WS_IDX    134217728
#define WS_VALS   (134217728 + 32768)
#define WS_ENERGY (134217728 + 65536)
#define WS_CNT    (134217728 + 98304)
#define WS_ROWS   (134217728 + 98560)

// ---------------- 0. init: zero per-expert row counters ----------------
__global__ void init_cnt_kernel(int* __restrict__ cnt) {
  if (threadIdx.x < E_) cnt[threadIdx.x] = 0;
}

// ---------------- 1. gating: one wave per row, f64; emit row lists ----------
__global__ __launch_bounds__(64) void gate_kernel(
    const float* __restrict__ x, const float* __restrict__ Wg,
    const float* __restrict__ bg, int* __restrict__ idx, float* __restrict__ vals,
    int* __restrict__ cnt, int* __restrict__ rows) {
  const int b = blockIdx.x;
  const int lane = threadIdx.x;
  double acc[E_];
#pragma unroll
  for (int e = 0; e < E_; ++e) acc[e] = 0.0;
  for (int d = lane; d < D_; d += 64) {
    double xv = (double)x[(size_t)b * D_ + d];
    const float* w = Wg + (size_t)d * E_;
#pragma unroll
    for (int e = 0; e < E_; ++e) acc[e] = fma(xv, (double)w[e], acc[e]);
  }
  for (int off = 32; off > 0; off >>= 1) {
#pragma unroll
    for (int e = 0; e < E_; ++e) acc[e] += __shfl_down(acc[e], off, 64);
  }
  if (lane == 0) {
    double logit[E_];
#pragma unroll
    for (int e = 0; e < E_; ++e) logit[e] = acc[e] + (double)bg[e];
    double m = logit[0];
#pragma unroll
    for (int e = 1; e < E_; ++e) m = fmax(m, logit[e]);
    double p[E_], s = 0.0;
#pragma unroll
    for (int e = 0; e < E_; ++e) { p[e] = exp(logit[e] - m); s += p[e]; }
#pragma unroll
    for (int e = 0; e < E_; ++e) p[e] = p[e] / s;
    unsigned taken = 0;
    for (int j = 0; j < K_; ++j) {
      int best = -1; double bv = -1.0;
#pragma unroll
      for (int e = 0; e < E_; ++e)
        if (!((taken >> e) & 1u) && p[e] > bv) { bv = p[e]; best = e; }
      taken |= (1u << best);
      idx[b * K_ + j] = best;
      vals[b * K_ + j] = (float)bv;
    }
    taken |= 1u;   // rep expert always needed
#pragma unroll
    for (int e = 0; e < E_; ++e) {
      if ((taken >> e) & 1u) {
        int p2 = atomicAdd(&cnt[e], 1);
        rows[e * B_ + p2] = b;
      }
    }
  }
}

// ---- 2. GEMM (f64 accumulate = truth), row-gathered per expert ----
// k-order identical to the verified full GEMM -> computed out_all bits identical.
#define BM 64
#define BN 64
#define BK 16

__global__ __launch_bounds__(256) void gemm_expert_kernel(
    const float* __restrict__ X, const float* __restrict__ We,
    const float* __restrict__ be, float* __restrict__ out_all,
    const int* __restrict__ cnt, const int* __restrict__ rows) {
  const int e  = blockIdx.z;
  const int nrows = cnt[e];
  const int m0 = blockIdx.y * BM;
  if (m0 >= nrows) return;
  const int n0 = blockIdx.x * BN;
  const float* Bmat = We + (size_t)e * D_ * H_;
  const int* rl = rows + e * B_;

  __shared__ double As[BK][BM + 1];
  __shared__ double Bs[BK][BN + 1];

  const int tid = threadIdx.x;
  const int tx = tid % 16, ty = tid / 16;
  const int arow  = tid / 4;
  const int acol4 = (tid % 4) * 4;
  const int brow  = tid / 16;
  const int bcol4 = (tid % 16) * 4;

  const int gidx = m0 + arow;
  const int grow = rl[(gidx < nrows) ? gidx : (nrows - 1)];

  double acc[4][4] = {};

  for (int k0 = 0; k0 < D_; k0 += BK) {
    float4 av = *(const float4*)(X + (size_t)grow * D_ + k0 + acol4);
    float4 bv = *(const float4*)(Bmat + (size_t)(k0 + brow) * H_ + n0 + bcol4);
    __syncthreads();
    As[acol4 + 0][arow] = (double)av.x;
    As[acol4 + 1][arow] = (double)av.y;
    As[acol4 + 2][arow] = (double)av.z;
    As[acol4 + 3][arow] = (double)av.w;
    Bs[brow][bcol4 + 0] = (double)bv.x;
    Bs[brow][bcol4 + 1] = (double)bv.y;
    Bs[brow][bcol4 + 2] = (double)bv.z;
    Bs[brow][bcol4 + 3] = (double)bv.w;
    __syncthreads();
#pragma unroll
    for (int kk = 0; kk < BK; ++kk) {
      double a0 = As[kk][ty * 4 + 0];
      double a1 = As[kk][ty * 4 + 1];
      double a2 = As[kk][ty * 4 + 2];
      double a3 = As[kk][ty * 4 + 3];
      double b0 = Bs[kk][tx * 4 + 0];
      double b1 = Bs[kk][tx * 4 + 1];
      double b2 = Bs[kk][tx * 4 + 2];
      double b3 = Bs[kk][tx * 4 + 3];
      acc[0][0] = fma(a0, b0, acc[0][0]);
      acc[0][1] = fma(a0, b1, acc[0][1]);
      acc[0][2] = fma(a0, b2, acc[0][2]);
      acc[0][3] = fma(a0, b3, acc[0][3]);
      acc[1][0] = fma(a1, b0, acc[1][0]);
      acc[1][1] = fma(a1, b1, acc[1][1]);
      acc[1][2] = fma(a1, b2, acc[1][2]);
      acc[1][3] = fma(a1, b3, acc[1][3]);
      acc[2][0] = fma(a2, b0, acc[2][0]);
      acc[2][1] = fma(a2, b1, acc[2][1]);
      acc[2][2] = fma(a2, b2, acc[2][2]);
      acc[2][3] = fma(a2, b3, acc[2][3]);
      acc[3][0] = fma(a3, b0, acc[3][0]);
      acc[3][1] = fma(a3, b1, acc[3][1]);
      acc[3][2] = fma(a3, b2, acc[3][2]);
      acc[3][3] = fma(a3, b3, acc[3][3]);
    }
  }
#pragma unroll
  for (int i = 0; i < 4; ++i) {
    const int ridx = m0 + ty * 4 + i;
    if (ridx < nrows) {
      const int m = rl[ridx];
      const int h = n0 + tx * 4;
      float4 o;
      o.x = (float)(acc[i][0] + (double)be[(size_t)e * H_ + h + 0]);
      o.y = (float)(acc[i][1] + (double)be[(size_t)e * H_ + h + 1]);
      o.z = (float)(acc[i][2] + (double)be[(size_t)e * H_ + h + 2]);
      o.w = (float)(acc[i][3] + (double)be[(size_t)e * H_ + h + 3]);
      *(float4*)(out_all + ((size_t)m * E_ + e) * H_ + h) = o;
    }
  }
}

// ---- 3. energy: bit-replica of numpy f32 logsumexp (verified R11) ----
__global__ __launch_bounds__(256) void energy_kernel(
    const float* __restrict__ out_all, const int* __restrict__ idx,
    float* __restrict__ energy) {
  const int b = blockIdx.x, j = blockIdx.y, t = threadIdx.x;
  const int e = idx[b * K_ + j];
  if (e == EXP_ID_) {
    if (t == 0) energy[b * K_ + j] = 1.0f + (float)log(2048.0);
    return;
  }
  const float* rep = out_all + ((size_t)b * E_ + EXP_ID_) * H_;
  const float* ok  = out_all + ((size_t)b * E_ + e) * H_;

  __shared__ float cs[H_];
  __shared__ float red[256];
  __shared__ float chain[128];

  float mx = -2.0f;
  for (int h = t; h < H_; h += 256) {
    float r = rep[h], o = ok[h];
    float num = r * o;
    float den = fabsf(r) * fabsf(o) + 1e-8f;
    float c = num / den;
    cs[h] = c;
    mx = fmaxf(mx, c);
  }
  red[t] = mx;
  __syncthreads();
  for (int off = 128; off > 0; off >>= 1) {
    if (t < off) red[t] = fmaxf(red[t], red[t + off]);
    __syncthreads();
  }
  const float m = red[0];
  __syncthreads();

  if (t < 128) {
    const int blk = t >> 3, jj = t & 7;
    const float* base = cs + blk * 128;
    float d0 = base[jj] - m;
    float r = (float)exp((double)d0);
#pragma unroll
    for (int q = 1; q < 16; ++q) {
      float dq = base[q * 8 + jj] - m;
      float term = (float)exp((double)dq);
      r = r + term;
    }
    chain[t] = r;
  }
  __syncthreads();

  if (t == 0) {
    float Bsum[16];
#pragma unroll
    for (int blk = 0; blk < 16; ++blk) {
      const float* c8 = chain + blk * 8;
      float s01 = c8[0] + c8[1];
      float s23 = c8[2] + c8[3];
      float s45 = c8[4] + c8[5];
      float s67 = c8[6] + c8[7];
      Bsum[blk] = (s01 + s23) + (s45 + s67);
    }
    float C[8], D[4], Ee[2];
#pragma unroll
    for (int i = 0; i < 8; ++i) C[i] = Bsum[2 * i] + Bsum[2 * i + 1];
#pragma unroll
    for (int i = 0; i < 4; ++i) D[i] = C[2 * i] + C[2 * i + 1];
#pragma unroll
    for (int i = 0; i < 2; ++i) Ee[i] = D[2 * i] + D[2 * i + 1];
    float S = Ee[0] + Ee[1];
    energy[b * K_ + j] = m + (float)log((double)S);
  }
}

// ---- 4. select: stable rank on f32 E bits (exact ties -> lower j), keep 6 ----
__global__ __launch_bounds__(256) void final_kernel(
    const float* __restrict__ out_all, const int* __restrict__ idx,
    const float* __restrict__ vals, const float* __restrict__ energy,
    float* __restrict__ out) {
  const int b = blockIdx.x;
  const int h = blockIdx.y * 256 + threadIdx.x;
  float En[K_];
#pragma unroll
  for (int j = 0; j < K_; ++j) En[j] = energy[b * K_ + j];
  double s = 0.0;
#pragma unroll
  for (int j = 0; j < K_; ++j) {
    int pos = 0;
#pragma unroll
    for (int j2 = 0; j2 < K_; ++j2)
      pos += (En[j2] < En[j]) || (En[j2] == En[j] && j2 < j);
    if (pos < KEEP_) {
      int e = idx[b * K_ + j];
      s += (double)vals[b * K_ + j] *
           (double)out_all[((size_t)b * E_ + e) * H_ + h];
    }
  }
  out[(size_t)b * H_ + h] = (float)s;
}

// ---------------- launch ----------------
extern "C" void kernel_launch(void* const* d_in, const int* in_sizes, int n_in,
                              void* d_out, int out_size, void* d_ws, size_t ws_size,
                              hipStream_t stream) {
  const float* x  = (const float*)d_in[0];
  const float* Wg = (const float*)d_in[1];
  const float* bg = (const float*)d_in[2];
  const float* We = (const float*)d_in[3];
  const float* be = (const float*)d_in[4];
  float* out = (float*)d_out;

  char* ws = (char*)d_ws;
  float* out_all = (float*)(ws + WS_OUTALL);
  int*   idx     = (int*)(ws + WS_IDX);
  float* vals    = (float*)(ws + WS_VALS);
  float* energy  = (float*)(ws + WS_ENERGY);
  int*   cnt     = (int*)(ws + WS_CNT);
  int*   rows    = (int*)(ws + WS_ROWS);

  init_cnt_kernel<<<dim3(1), dim3(64), 0, stream>>>(cnt);

  gate_kernel<<<dim3(B_), dim3(64), 0, stream>>>(x, Wg, bg, idx, vals, cnt, rows);

  gemm_expert_kernel<<<dim3(H_ / BN, B_ / BM, E_), dim3(256), 0, stream>>>(
      x, We, be, out_all, cnt, rows);

  energy_kernel<<<dim3(B_, K_), dim3(256), 0, stream>>>(out_all, idx, energy);

  final_kernel<<<dim3(B_, H_ / 256), dim3(256), 0, stream>>>(
      out_all, idx, vals, energy, out);
}

// Round 13
// 1775.423 us; speedup vs baseline: 2.1438x; 2.1438x over previous
//
#include <hip/hip_runtime.h>
#include <math.h>

#define B_ 1024
#define D_ 2048
#define H_ 2048
#define E_ 16
#define K_ 8
#define KEEP_ 6
#define EXP_ID_ 0

// ---------------- ws layout ----------------
#define WS_OUTALL 0
#define WS_IDX    134217728
#define WS_VALS   (134217728 + 32768)
#define WS_ENERGY (134217728 + 65536)
#define WS_CNT    (134217728 + 98304)
#define WS_ROWS   (134217728 + 98560)

// ---------------- 0. init: zero per-expert row counters ----------------
__global__ void init_cnt_kernel(int* __restrict__ cnt) {
  if (threadIdx.x < E_) cnt[threadIdx.x] = 0;
}

// ---------------- 1. gating: one wave per row, f64; emit row lists ----------
__global__ __launch_bounds__(64) void gate_kernel(
    const float* __restrict__ x, const float* __restrict__ Wg,
    const float* __restrict__ bg, int* __restrict__ idx, float* __restrict__ vals,
    int* __restrict__ cnt, int* __restrict__ rows) {
  const int b = blockIdx.x;
  const int lane = threadIdx.x;
  double acc[E_];
#pragma unroll
  for (int e = 0; e < E_; ++e) acc[e] = 0.0;
  for (int d = lane; d < D_; d += 64) {
    double xv = (double)x[(size_t)b * D_ + d];
    const float* w = Wg + (size_t)d * E_;
#pragma unroll
    for (int e = 0; e < E_; ++e) acc[e] = fma(xv, (double)w[e], acc[e]);
  }
  for (int off = 32; off > 0; off >>= 1) {
#pragma unroll
    for (int e = 0; e < E_; ++e) acc[e] += __shfl_down(acc[e], off, 64);
  }
  if (lane == 0) {
    double logit[E_];
#pragma unroll
    for (int e = 0; e < E_; ++e) logit[e] = acc[e] + (double)bg[e];
    double m = logit[0];
#pragma unroll
    for (int e = 1; e < E_; ++e) m = fmax(m, logit[e]);
    double p[E_], s = 0.0;
#pragma unroll
    for (int e = 0; e < E_; ++e) { p[e] = exp(logit[e] - m); s += p[e]; }
#pragma unroll
    for (int e = 0; e < E_; ++e) p[e] = p[e] / s;
    unsigned taken = 0;
    for (int j = 0; j < K_; ++j) {
      int best = -1; double bv = -1.0;
#pragma unroll
      for (int e = 0; e < E_; ++e)
        if (!((taken >> e) & 1u) && p[e] > bv) { bv = p[e]; best = e; }
      taken |= (1u << best);
      idx[b * K_ + j] = best;
      vals[b * K_ + j] = (float)bv;
    }
    taken |= 1u;   // rep expert always needed
#pragma unroll
    for (int e = 0; e < E_; ++e) {
      if ((taken >> e) & 1u) {
        int p2 = atomicAdd(&cnt[e], 1);
        rows[e * B_ + p2] = b;
      }
    }
  }
}

// ---- 2. GEMM (f64 accumulate = truth), row-gathered, conflict-free LDS ----
// Per-output sequential k-order identical to verified R11 -> bits identical.
#define BM 64
#define BN 64
#define BK 16

__global__ __launch_bounds__(256) void gemm_expert_kernel(
    const float* __restrict__ X, const float* __restrict__ We,
    const float* __restrict__ be, float* __restrict__ out_all,
    const int* __restrict__ cnt, const int* __restrict__ rows) {
  const int e  = blockIdx.z;
  const int nrows = cnt[e];
  const int m0 = blockIdx.y * BM;
  if (m0 >= nrows) return;
  const int n0 = blockIdx.x * BN;
  const float* Bmat = We + (size_t)e * D_ * H_;
  const int* rl = rows + e * B_;

  __shared__ double As[BM][BK + 2];   // row-major, stride 18 (144B, 16B-aligned)
  __shared__ double Bs[BK][BN + 2];   // stride 66 (528B, 16B-aligned)

  const int tid = threadIdx.x;
  const int tx = tid % 16, ty = tid / 16;   // ty in [0,16): 4 output rows each
  const int arow  = tid / 4;                // [0,64)
  const int acol4 = (tid % 4) * 4;          // {0,4,8,12}
  const int brow  = tid / 16;               // [0,16)
  const int bcol4 = (tid % 16) * 4;         // {0..60}

  const int gidx = m0 + arow;
  const int grow = rl[(gidx < nrows) ? gidx : (nrows - 1)];

  // lane's 4 output cols: {c0, c0+1, c1, c1+1}
  const int c0 = tx * 2;
  const int c1 = tx * 2 + 32;

  double acc[4][4] = {};

  for (int k0 = 0; k0 < D_; k0 += BK) {
    float4 av = *(const float4*)(X + (size_t)grow * D_ + k0 + acol4);
    float4 bv = *(const float4*)(Bmat + (size_t)(k0 + brow) * H_ + n0 + bcol4);
    __syncthreads();
    {
      double2 w0 = make_double2((double)av.x, (double)av.y);
      double2 w1 = make_double2((double)av.z, (double)av.w);
      *(double2*)&As[arow][acol4 + 0] = w0;   // ds_write_b128
      *(double2*)&As[arow][acol4 + 2] = w1;
      double2 v0 = make_double2((double)bv.x, (double)bv.y);
      double2 v1 = make_double2((double)bv.z, (double)bv.w);
      *(double2*)&Bs[brow][bcol4 + 0] = v0;
      *(double2*)&Bs[brow][bcol4 + 2] = v1;
    }
    __syncthreads();
#pragma unroll
    for (int kk = 0; kk < BK; ++kk) {
      double a0 = As[ty * 4 + 0][kk];
      double a1 = As[ty * 4 + 1][kk];
      double a2 = As[ty * 4 + 2][kk];
      double a3 = As[ty * 4 + 3][kk];
      double2 b01 = *(const double2*)&Bs[kk][c0];   // 16B lane stride: 2-way
      double2 b23 = *(const double2*)&Bs[kk][c1];
      acc[0][0] = fma(a0, b01.x, acc[0][0]);
      acc[0][1] = fma(a0, b01.y, acc[0][1]);
      acc[0][2] = fma(a0, b23.x, acc[0][2]);
      acc[0][3] = fma(a0, b23.y, acc[0][3]);
      acc[1][0] = fma(a1, b01.x, acc[1][0]);
      acc[1][1] = fma(a1, b01.y, acc[1][1]);
      acc[1][2] = fma(a1, b23.x, acc[1][2]);
      acc[1][3] = fma(a1, b23.y, acc[1][3]);
      acc[2][0] = fma(a2, b01.x, acc[2][0]);
      acc[2][1] = fma(a2, b01.y, acc[2][1]);
      acc[2][2] = fma(a2, b23.x, acc[2][2]);
      acc[2][3] = fma(a2, b23.y, acc[2][3]);
      acc[3][0] = fma(a3, b01.x, acc[3][0]);
      acc[3][1] = fma(a3, b01.y, acc[3][1]);
      acc[3][2] = fma(a3, b23.x, acc[3][2]);
      acc[3][3] = fma(a3, b23.y, acc[3][3]);
    }
  }
#pragma unroll
  for (int i = 0; i < 4; ++i) {
    const int ridx = m0 + ty * 4 + i;
    if (ridx < nrows) {
      const int m = rl[ridx];
      float* dst = out_all + ((size_t)m * E_ + e) * H_;
      float2 p0, p1;
      p0.x = (float)(acc[i][0] + (double)be[(size_t)e * H_ + n0 + c0 + 0]);
      p0.y = (float)(acc[i][1] + (double)be[(size_t)e * H_ + n0 + c0 + 1]);
      p1.x = (float)(acc[i][2] + (double)be[(size_t)e * H_ + n0 + c1 + 0]);
      p1.y = (float)(acc[i][3] + (double)be[(size_t)e * H_ + n0 + c1 + 1]);
      *(float2*)(dst + n0 + c0) = p0;
      *(float2*)(dst + n0 + c1) = p1;
    }
  }
}

// ---- 3. energy: bit-replica of numpy f32 logsumexp (verified R11) ----
__global__ __launch_bounds__(256) void energy_kernel(
    const float* __restrict__ out_all, const int* __restrict__ idx,
    float* __restrict__ energy) {
  const int b = blockIdx.x, j = blockIdx.y, t = threadIdx.x;
  const int e = idx[b * K_ + j];
  if (e == EXP_ID_) {
    if (t == 0) energy[b * K_ + j] = 1.0f + (float)log(2048.0);
    return;
  }
  const float* rep = out_all + ((size_t)b * E_ + EXP_ID_) * H_;
  const float* ok  = out_all + ((size_t)b * E_ + e) * H_;

  __shared__ float cs[H_];
  __shared__ float red[256];
  __shared__ float chain[128];

  float mx = -2.0f;
  for (int h = t; h < H_; h += 256) {
    float r = rep[h], o = ok[h];
    float num = r * o;
    float den = fabsf(r) * fabsf(o) + 1e-8f;
    float c = num / den;
    cs[h] = c;
    mx = fmaxf(mx, c);
  }
  red[t] = mx;
  __syncthreads();
  for (int off = 128; off > 0; off >>= 1) {
    if (t < off) red[t] = fmaxf(red[t], red[t + off]);
    __syncthreads();
  }
  const float m = red[0];
  __syncthreads();

  if (t < 128) {
    const int blk = t >> 3, jj = t & 7;
    const float* base = cs + blk * 128;
    float d0 = base[jj] - m;
    float r = (float)exp((double)d0);
#pragma unroll
    for (int q = 1; q < 16; ++q) {
      float dq = base[q * 8 + jj] - m;
      float term = (float)exp((double)dq);
      r = r + term;
    }
    chain[t] = r;
  }
  __syncthreads();

  if (t == 0) {
    float Bsum[16];
#pragma unroll
    for (int blk = 0; blk < 16; ++blk) {
      const float* c8 = chain + blk * 8;
      float s01 = c8[0] + c8[1];
      float s23 = c8[2] + c8[3];
      float s45 = c8[4] + c8[5];
      float s67 = c8[6] + c8[7];
      Bsum[blk] = (s01 + s23) + (s45 + s67);
    }
    float C[8], D[4], Ee[2];
#pragma unroll
    for (int i = 0; i < 8; ++i) C[i] = Bsum[2 * i] + Bsum[2 * i + 1];
#pragma unroll
    for (int i = 0; i < 4; ++i) D[i] = C[2 * i] + C[2 * i + 1];
#pragma unroll
    for (int i = 0; i < 2; ++i) Ee[i] = D[2 * i] + D[2 * i + 1];
    float S = Ee[0] + Ee[1];
    energy[b * K_ + j] = m + (float)log((double)S);
  }
}

// ---- 4. select: stable rank on f32 E bits (exact ties -> lower j), keep 6 ----
__global__ __launch_bounds__(256) void final_kernel(
    const float* __restrict__ out_all, const int* __restrict__ idx,
    const float* __restrict__ vals, const float* __restrict__ energy,
    float* __restrict__ out) {
  const int b = blockIdx.x;
  const int h = blockIdx.y * 256 + threadIdx.x;
  float En[K_];
#pragma unroll
  for (int j = 0; j < K_; ++j) En[j] = energy[b * K_ + j];
  double s = 0.0;
#pragma unroll
  for (int j = 0; j < K_; ++j) {
    int pos = 0;
#pragma unroll
    for (int j2 = 0; j2 < K_; ++j2)
      pos += (En[j2] < En[j]) || (En[j2] == En[j] && j2 < j);
    if (pos < KEEP_) {
      int e = idx[b * K_ + j];
      s += (double)vals[b * K_ + j] *
           (double)out_all[((size_t)b * E_ + e) * H_ + h];
    }
  }
  out[(size_t)b * H_ + h] = (float)s;
}

// ---------------- launch ----------------
extern "C" void kernel_launch(void* const* d_in, const int* in_sizes, int n_in,
                              void* d_out, int out_size, void* d_ws, size_t ws_size,
                              hipStream_t stream) {
  const float* x  = (const float*)d_in[0];
  const float* Wg = (const float*)d_in[1];
  const float* bg = (const float*)d_in[2];
  const float* We = (const float*)d_in[3];
  const float* be = (const float*)d_in[4];
  float* out = (float*)d_out;

  char* ws = (char*)d_ws;
  float* out_all = (float*)(ws + WS_OUTALL);
  int*   idx     = (int*)(ws + WS_IDX);
  float* vals    = (float*)(ws + WS_VALS);
  float* energy  = (float*)(ws + WS_ENERGY);
  int*   cnt     = (int*)(ws + WS_CNT);
  int*   rows    = (int*)(ws + WS_ROWS);

  init_cnt_kernel<<<dim3(1), dim3(64), 0, stream>>>(cnt);

  gate_kernel<<<dim3(B_), dim3(64), 0, stream>>>(x, Wg, bg, idx, vals, cnt, rows);

  gemm_expert_kernel<<<dim3(H_ / BN, B_ / BM, E_), dim3(256), 0, stream>>>(
      x, We, be, out_all, cnt, rows);

  energy_kernel<<<dim3(B_, K_), dim3(256), 0, stream>>>(out_all, idx, energy);

  final_kernel<<<dim3(B_, H_ / 256), dim3(256), 0, stream>>>(
      out_all, idx, vals, energy, out);
}